// Round 5
// baseline (747.302 us; speedup 1.0000x reference)
//
#include <hip/hip_runtime.h>
#include <stdint.h>

typedef short bf16x8 __attribute__((ext_vector_type(8)));
typedef float f32x4 __attribute__((ext_vector_type(4)));
typedef unsigned short u16x4 __attribute__((ext_vector_type(4)));
typedef unsigned short ushort_t;

__device__ __forceinline__ float bf2f(unsigned short u) {
    union { unsigned int i; float f; } v; v.i = ((unsigned int)u) << 16; return v.f;
}
__device__ __forceinline__ unsigned short f2bf(float f) {
    union { float f; unsigned int i; } v; v.f = f;
    unsigned int r = (v.i + 0x7FFFu + ((v.i >> 16) & 1u)) >> 16;
    return (unsigned short)r;
}

// async global->LDS, 16B per lane; LDS dest = wave-uniform base + lane*16
__device__ __forceinline__ void gload_lds16(const void* g, void* l) {
    __builtin_amdgcn_global_load_lds(
        (const __attribute__((address_space(1))) void*)g,
        (__attribute__((address_space(3))) void*)l, 16, 0, 0);
}

// Dtype-polymorphic loaders. F32=true: buffers are float32. F32=false: bf16.
template <bool F32> struct LD;
template <> struct LD<false> {
    static __device__ __forceinline__ float s(const void* p, size_t i) {
        return bf2f(((const ushort_t*)p)[i]);
    }
    static __device__ __forceinline__ bf16x8 v8(const void* p, size_t i) {
        return *reinterpret_cast<const bf16x8*>((const ushort_t*)p + i);
    }
};
template <> struct LD<true> {
    static __device__ __forceinline__ float s(const void* p, size_t i) {
        return ((const float*)p)[i];
    }
    static __device__ __forceinline__ bf16x8 v8(const void* p, size_t i) {
        const float* f = (const float*)p + i;
        float4 a = *reinterpret_cast<const float4*>(f);
        float4 b = *reinterpret_cast<const float4*>(f + 4);
        bf16x8 r;
        r[0] = (short)f2bf(a.x); r[1] = (short)f2bf(a.y);
        r[2] = (short)f2bf(a.z); r[3] = (short)f2bf(a.w);
        r[4] = (short)f2bf(b.x); r[5] = (short)f2bf(b.y);
        r[6] = (short)f2bf(b.z); r[7] = (short)f2bf(b.w);
        return r;
    }
};

// ---------------- K0: dtype probe ----------------
__global__ __launch_bounds__(64) void kprobe(const ushort_t* __restrict__ pos, int* __restrict__ dt) {
    float v = bf2f(pos[2 * threadIdx.x]);
    bool sane = (v >= 0.0f) && (v <= 1.0f);
    unsigned long long b = __ballot(sane);
    if (threadIdx.x == 0) dt[0] = (b == ~0ULL) ? 1 : 0;  // 1 = bf16, 0 = f32
}

// ---------------- K1: global max of pos per coordinate ----------------
template <bool F32>
static __device__ __forceinline__ void kpos_body(const void* pos, int* pmax, float* s0, float* s1) {
    int p = blockIdx.x * 256 + threadIdx.x;
    s0[threadIdx.x] = LD<F32>::s(pos, 2 * (size_t)p);
    s1[threadIdx.x] = LD<F32>::s(pos, 2 * (size_t)p + 1);
    __syncthreads();
    for (int off = 128; off > 0; off >>= 1) {
        if (threadIdx.x < (unsigned)off) {
            s0[threadIdx.x] = fmaxf(s0[threadIdx.x], s0[threadIdx.x + off]);
            s1[threadIdx.x] = fmaxf(s1[threadIdx.x], s1[threadIdx.x + off]);
        }
        __syncthreads();
    }
    if (threadIdx.x == 0) {
        atomicMax(&pmax[0], __float_as_int(s0[0]));
        atomicMax(&pmax[1], __float_as_int(s1[0]));
    }
}
__global__ __launch_bounds__(256) void kpos_max(const int* __restrict__ dt, const void* __restrict__ pos,
                                                int* __restrict__ pmax) {
    __shared__ float s0[256], s1[256];
    if (dt[0]) kpos_body<false>(pos, pmax, s0, s1);
    else       kpos_body<true>(pos, pmax, s0, s1);
}

// ---------------- K2: per-key bias tb[p][h] = pos_n . pos_w + maskterm ----------------
template <bool F32>
static __device__ __forceinline__ void ktb_body(const void* pos, const void* pos_w, const int* mask,
                                                const int* pmax, float* tb) {
    int p = blockIdx.x * 256 + threadIdx.x;
    float inv0 = 1.0f / __int_as_float(pmax[0]);
    float inv1 = 1.0f / __int_as_float(pmax[1]);
    float x0 = LD<F32>::s(pos, 2 * (size_t)p) * inv0;
    float x1 = LD<F32>::s(pos, 2 * (size_t)p + 1) * inv1;
    float mterm = mask[p] ? 0.0f : -100.0f;
#pragma unroll
    for (int h = 0; h < 8; h++)
        tb[p * 8 + h] = x0 * LD<F32>::s(pos_w, h) + x1 * LD<F32>::s(pos_w, 8 + h) + mterm;
}
__global__ __launch_bounds__(256) void ktb(const int* __restrict__ dt, const void* __restrict__ pos,
                                           const void* __restrict__ pos_w, const int* __restrict__ mask,
                                           const int* __restrict__ pmax, float* __restrict__ tb) {
    if (dt[0]) ktb_body<false>(pos, pos_w, mask, pmax, tb);
    else       ktb_body<true>(pos, pos_w, mask, pmax, tb);
}

// ---------------- Kb: biases -> f32 ----------------
__global__ __launch_bounds__(256) void kbias(const int* __restrict__ dt, const void* __restrict__ qkv_b,
                                             const void* __restrict__ proj_b,
                                             float* __restrict__ qb, float* __restrict__ pb) {
    int i = blockIdx.x * 256 + threadIdx.x;
    if (dt[0]) {
        if (i < 1536) qb[i] = bf2f(((const ushort_t*)qkv_b)[i]);
        if (i < 512)  pb[i] = bf2f(((const ushort_t*)proj_b)[i]);
    } else {
        if (i < 1536) qb[i] = ((const float*)qkv_b)[i];
        if (i < 512)  pb[i] = ((const float*)proj_b)[i];
    }
}

// ---------------- Kf: feat -> bf16 once ----------------
template <bool F32>
static __device__ __forceinline__ void kfeat_body(const void* feat, ushort_t* featb) {
    for (size_t t = (size_t)blockIdx.x * 256 + threadIdx.x; t < 4194304; t += (size_t)gridDim.x * 256) {
        *reinterpret_cast<bf16x8*>(featb + t * 8) = LD<F32>::v8(feat, t * 8);
    }
}
__global__ __launch_bounds__(256) void kfeat(const int* __restrict__ dt, const void* __restrict__ feat,
                                             ushort_t* __restrict__ featb) {
    if (dt[0]) kfeat_body<false>(feat, featb);
    else       kfeat_body<true>(feat, featb);
}

// ---------------- Kt: transpose (R x C -> C x R) into bf16, 64x64 tiles ----------------
template <bool F32>
static __device__ __forceinline__ void ktrans_body(const void* src, ushort_t* dst, int R, int C,
                                                   ushort_t* tile /*64x65*/) {
    int nbc = C >> 6;
    int rb = (blockIdx.x / nbc) << 6;
    int cb = (blockIdx.x % nbc) << 6;
    for (int i = threadIdx.x; i < 4096; i += 256) {
        int r = i >> 6, c = i & 63;
        tile[r * 65 + c] = f2bf(LD<F32>::s(src, (size_t)(rb + r) * C + cb + c));
    }
    __syncthreads();
    for (int i = threadIdx.x; i < 4096; i += 256) {
        int rr = i & 63, cc = i >> 6;
        dst[(size_t)(cb + cc) * R + rb + rr] = tile[rr * 65 + cc];
    }
}
__global__ __launch_bounds__(256) void ktrans(const int* __restrict__ dt, const void* __restrict__ src,
                                              ushort_t* __restrict__ dst, int R, int C) {
    __shared__ ushort_t tile[64 * 65];
    if (dt[0]) ktrans_body<false>(src, dst, R, C, tile);
    else       ktrans_body<true>(src, dst, R, C, tile);
}

// ---------------- K3: fused QKV projection + attention, 80KB LDS -> 2 blocks/CU ----------------
// 512 threads = 8 waves. LDS (81920B exactly = 160KB/2):
//   sVt [64][256] 32KB | sK [256][64] 32KB | Cr 16KB (W dbuf 2x4KB / Q bounce / P scratch)
// All tiles unpadded; bank balance via chunk-XOR: 16B-chunk index ^= (row&7)  (or &3 for
// 4-chunk rows). Phase A = 3 passes (Q,K,V), acc[4][2] each; Q goes to registers via a
// 2-half bounce through Cr. Phase B identical math to R2. The point: 2 resident blocks/CU
// so one block's VALU-heavy softmax overlaps the other's MFMA/staging (m114 co-schedule).
template <bool F32>
static __device__ __forceinline__ void kattn_body(const void* feat, const ushort_t* qkv_wt,
                                                  const float* qb, const float* tb, ushort_t* xout,
                                                  ushort_t* smem) {
    const int tid = threadIdx.x;
    const int lane = tid & 63;
    const int wave = tid >> 6;   // 0..7
    const int quad = lane >> 4;
    const int l15 = lane & 15;

    // XCD decode: 8 clusters x 8 heads co-resident per XCD per round (2 blocks/CU, 4 rounds)
    const int bx = blockIdx.x;
    const int xcd = bx & 7;
    const int jj = bx >> 3;          // 0..255
    const int rnd = jj >> 6;         // 0..3
    const int slot = jj & 63;
    const int kc = xcd * 32 + rnd * 8 + (slot >> 3);
    const int h = slot & 7;

    ushort_t* sVt = smem;            // u16[16384]  [d=64][m=256]
    ushort_t* sK  = smem + 16384;    // u16[16384]  [m=256][d=64]
    ushort_t* Cr  = smem + 32768;    // u16[8192]   scratch
    char* CrB = (char*)Cr;

    const int wrow = (wave >> 1) * 64;   // 4 row groups
    const int wcol = (wave & 1) * 32;    // 2 col groups within the pass's 64 cols

    // W staging: threads 0..255 stage 64 rows x 4 chunks, source chunk pre-swizzled
    const int lc = (tid & 255) >> 2;
    const int chs = (tid & 3) ^ (lc & 3);
    const bool stager = (tid < 256);

    const size_t fbase = (size_t)(kc * 256) * 512;
    bf16x8 aQ[2][2];

    // ---- Phase A: 3 passes over out-cols {Q, K, V} ----
#pragma unroll
    for (int p = 0; p < 3; p++) {
        const ushort_t* gW = qkv_wt + (size_t)(p * 512 + h * 64 + lc) * 512 + chs * 8;
        f32x4 acc[4][2];
#pragma unroll
        for (int rt = 0; rt < 4; rt++)
#pragma unroll
            for (int ct = 0; ct < 2; ct++) { f32x4 z = {0.0f, 0.0f, 0.0f, 0.0f}; acc[rt][ct] = z; }

        if (stager) gload_lds16(gW, CrB + (tid & 255) * 16);
        __syncthreads();

#pragma unroll 2
        for (int c = 0; c < 16; c++) {
            if (c < 15 && stager)
                gload_lds16(gW + (c + 1) * 32, CrB + ((c + 1) & 1) * 4096 + (tid & 255) * 16);
            bf16x8 af[4];
#pragma unroll
            for (int rt = 0; rt < 4; rt++)
                af[rt] = LD<F32>::v8(feat, fbase + (size_t)(wrow + rt * 16 + l15) * 512 + c * 32 + quad * 8);
            bf16x8 bw[2];
#pragma unroll
            for (int ct = 0; ct < 2; ct++) {
                int rw = wcol + ct * 16 + l15;
                bw[ct] = *reinterpret_cast<const bf16x8*>(
                    Cr + (c & 1) * 2048 + rw * 32 + (quad ^ (rw & 3)) * 8);
            }
#pragma unroll
            for (int ct = 0; ct < 2; ct++)
#pragma unroll
                for (int rt = 0; rt < 4; rt++)
                    acc[rt][ct] = __builtin_amdgcn_mfma_f32_16x16x32_bf16(af[rt], bw[ct], acc[rt][ct], 0, 0, 0);
            __syncthreads();
        }

        if (p == 0) {
            // Q: scale+bias, then bounce to per-wave A-fragments via Cr in 2 halves
            ushort_t qv[2][4][4];
#pragma unroll
            for (int ct = 0; ct < 2; ct++) {
                int col = wcol + ct * 16 + l15;
                float bias = qb[h * 64 + col];
#pragma unroll
                for (int rt = 0; rt < 4; rt++)
#pragma unroll
                    for (int r = 0; r < 4; r++)
                        qv[ct][rt][r] = f2bf((acc[rt][ct][r] + bias) * 0.125f);
            }
#pragma unroll
            for (int half = 0; half < 2; half++) {
                if ((wrow >> 7) == half) {
#pragma unroll
                    for (int ct = 0; ct < 2; ct++) {
                        int col = wcol + ct * 16 + l15;
#pragma unroll
                        for (int rt = 0; rt < 4; rt++)
#pragma unroll
                            for (int r = 0; r < 4; r++) {
                                int m = wrow + rt * 16 + quad * 4 + r;
                                Cr[(m & 127) * 64 + (((col >> 3) ^ (m & 7)) * 8) + (col & 7)] =
                                    qv[ct][rt][r];
                            }
                    }
                }
                __syncthreads();
                if ((wave >> 2) == half) {
#pragma unroll
                    for (int rt = 0; rt < 2; rt++)
#pragma unroll
                        for (int s = 0; s < 2; s++) {
                            int row = wave * 32 + rt * 16 + l15;
                            aQ[rt][s] = *reinterpret_cast<const bf16x8*>(
                                Cr + (row & 127) * 64 + (((s * 4 + quad) ^ (row & 7)) * 8));
                        }
                }
                __syncthreads();
            }
        } else if (p == 1) {
#pragma unroll
            for (int ct = 0; ct < 2; ct++) {
                int col = wcol + ct * 16 + l15;
                float bias = qb[512 + h * 64 + col];
#pragma unroll
                for (int rt = 0; rt < 4; rt++)
#pragma unroll
                    for (int r = 0; r < 4; r++) {
                        int m = wrow + rt * 16 + quad * 4 + r;
                        sK[m * 64 + (((col >> 3) ^ (m & 7)) * 8) + (col & 7)] =
                            f2bf(acc[rt][ct][r] + bias);
                    }
            }
        } else {
#pragma unroll
            for (int ct = 0; ct < 2; ct++) {
                int hd_ = wcol + ct * 16 + l15;
                float bias = qb[1024 + h * 64 + hd_];
#pragma unroll
                for (int rt = 0; rt < 4; rt++) {
                    int m0 = wrow + rt * 16 + quad * 4;
                    u16x4 vp;
#pragma unroll
                    for (int r = 0; r < 4; r++) vp[r] = f2bf(acc[rt][ct][r] + bias);
                    *reinterpret_cast<u16x4*>(
                        &sVt[hd_ * 256 + (((m0 >> 3) ^ (hd_ & 7)) * 8) + (m0 & 7)]) = vp;
                }
            }
        }
    }
    __syncthreads();

    // ---- Phase B: S = Q K^T + bias, exp, P@V, normalize (math identical to R2) ----
    f32x4 accO[2][4];
    float rs[2][4];
#pragma unroll
    for (int rt = 0; rt < 2; rt++)
#pragma unroll
        for (int ct = 0; ct < 4; ct++) {
            f32x4 z = {0.0f, 0.0f, 0.0f, 0.0f};
            accO[rt][ct] = z;
            rs[rt][ct] = 0.0f;  // rs[rt][r]
        }

    ushort_t* sPw = Cr + wave * 1024;  // 2KB per wave, 32 rows x 32 cols (s-halves share it)

    for (int jb = 0; jb < 4; jb++) {
        int kb = jb * 64;
        float tc[4];
#pragma unroll
        for (int ctk = 0; ctk < 4; ctk++)
            tc[ctk] = tb[(size_t)(kc * 256 + kb + ctk * 16 + l15) * 8 + h];
        bf16x8 bK[4][2];
#pragma unroll
        for (int ctk = 0; ctk < 4; ctk++)
#pragma unroll
            for (int s = 0; s < 2; s++) {
                int row = kb + ctk * 16 + l15;
                bK[ctk][s] = *reinterpret_cast<const bf16x8*>(
                    sK + row * 64 + (((s * 4 + quad) ^ (row & 7)) * 8));
            }

#pragma unroll
        for (int sh = 0; sh < 2; sh++) {
#pragma unroll
            for (int ck = 0; ck < 2; ck++) {
                int ctk = sh * 2 + ck;
                float tcol = tc[ctk];
#pragma unroll
                for (int rt = 0; rt < 2; rt++) {
                    f32x4 sa = {0.0f, 0.0f, 0.0f, 0.0f};
                    sa = __builtin_amdgcn_mfma_f32_16x16x32_bf16(aQ[rt][0], bK[ctk][0], sa, 0, 0, 0);
                    sa = __builtin_amdgcn_mfma_f32_16x16x32_bf16(aQ[rt][1], bK[ctk][1], sa, 0, 0, 0);
#pragma unroll
                    for (int r = 0; r < 4; r++) {
                        float pexp = __expf(sa[r] + tcol);  // |S|<~5, masked ~ -100, safe in f32
                        rs[rt][r] += pexp;
                        int prow = rt * 16 + quad * 4 + r;
                        sPw[prow * 32 + (((ck * 2 + (l15 >> 3)) ^ (prow & 3)) * 8) + (l15 & 7)] =
                            f2bf(pexp);
                    }
                }
            }
            // P @ V for this s-half (wave-private scratch, same-wave DS ordering, no barrier)
#pragma unroll
            for (int rt = 0; rt < 2; rt++) {
                bf16x8 aP = *reinterpret_cast<const bf16x8*>(
                    sPw + (rt * 16 + l15) * 32 + ((quad ^ (l15 & 3)) * 8));
#pragma unroll
                for (int ct = 0; ct < 4; ct++) {
                    int vrow = ct * 16 + l15;
                    bf16x8 bV = *reinterpret_cast<const bf16x8*>(
                        sVt + vrow * 256 + (((jb * 8 + sh * 4 + quad) ^ (vrow & 7)) * 8));
                    accO[rt][ct] = __builtin_amdgcn_mfma_f32_16x16x32_bf16(aP, bV, accO[rt][ct], 0, 0, 0);
                }
            }
        }
    }

    // Row sums: butterfly over the 16 lanes sharing a quad
    float inv_[2][4];
#pragma unroll
    for (int rt = 0; rt < 2; rt++)
#pragma unroll
        for (int r = 0; r < 4; r++) {
            float v = rs[rt][r];
            v += __shfl_xor(v, 1, 64);
            v += __shfl_xor(v, 2, 64);
            v += __shfl_xor(v, 4, 64);
            v += __shfl_xor(v, 8, 64);
            inv_[rt][r] = 1.0f / v;
        }

#pragma unroll
    for (int rt = 0; rt < 2; rt++)
#pragma unroll
        for (int ct = 0; ct < 4; ct++)
#pragma unroll
            for (int r = 0; r < 4; r++) {
                int m = wave * 32 + rt * 16 + quad * 4 + r;
                xout[((size_t)(kc * 256 + m)) * 512 + h * 64 + ct * 16 + l15] =
                    f2bf(accO[rt][ct][r] * inv_[rt][r]);
            }
}
__global__ __launch_bounds__(512, 4) void kattn_bf(const ushort_t* __restrict__ featb,
                                                   const ushort_t* __restrict__ qkv_wt,
                                                   const float* __restrict__ qb,
                                                   const float* __restrict__ tb, ushort_t* __restrict__ xout) {
    __shared__ ushort_t smem[40960];  // 81920 B = exactly 160KB/2 -> 2 blocks/CU
    kattn_body<false>(featb, qkv_wt, qb, tb, xout, smem);
}
__global__ __launch_bounds__(512, 4) void kattn_dyn(const int* __restrict__ dt, const void* __restrict__ feat,
                                                    const ushort_t* __restrict__ qkv_wt,
                                                    const float* __restrict__ qb,
                                                    const float* __restrict__ tb, ushort_t* __restrict__ xout) {
    __shared__ ushort_t smem[40960];
    if (dt[0]) kattn_body<false>(feat, qkv_wt, qb, tb, xout, smem);
    else       kattn_body<true>(feat, qkv_wt, qb, tb, xout, smem);
}

// ---------------- K4: out = x @ proj_w + proj_b ----------------
// 512 threads (8 waves), tile 256x128 (4 rowg x 2 colg, acc[4][4]),
// 16KB LDS dbuf -> 2 blocks/CU -> 4 waves/SIMD. XCD decode keeps the
// 4 col-blocks of one x row-panel region on one XCD.
template <bool F32>
static __device__ __forceinline__ void kproj_body(const ushort_t* x, const ushort_t* proj_wt,
                                                  const float* pb, void* out, ushort_t* sW) {
    const int tid = threadIdx.x;
    const int lane = tid & 63;
    const int wave = tid >> 6;   // 0..7
    const int quad = lane >> 4;
    const int l15 = lane & 15;
    const int bx = blockIdx.x;
    const int xcd = bx & 7;
    const int j = bx >> 3;                           // 0..127
    const int rowb = (xcd * 32 + (j >> 2)) * 256;    // 256-row panel
    const int colb = (j & 3) * 128;                  // 128-col block
    const int rowg = (wave >> 1) * 64;
    const int colg = (wave & 1) * 64;
    char* ldsW = (char*)sW;

    // staging: 512 tasks = 128 rows x 4 chunks(16B); 1 per thread, source-swizzled
    const int lc = tid >> 2, ch = (tid & 3) ^ ((lc >> 1) & 3);
    const ushort_t* g1 = proj_wt + (size_t)(colb + lc) * 512 + ch * 8;
    const int swz = (l15 >> 1) & 3;

    f32x4 acc[4][4];
#pragma unroll
    for (int rt = 0; rt < 4; rt++)
#pragma unroll
        for (int ct = 0; ct < 4; ct++) {
            f32x4 z = {0.0f, 0.0f, 0.0f, 0.0f};
            acc[rt][ct] = z;
        }

    gload_lds16(g1, ldsW + wave * 1024);
    __syncthreads();

#pragma unroll 2
    for (int c = 0; c < 16; c++) {
        const int cb = (c & 1) * 4096;  // u16 offset of current buf
        if (c < 15)
            gload_lds16(g1 + (c + 1) * 32, ldsW + ((c + 1) & 1) * 8192 + wave * 1024);
        bf16x8 af[4];
#pragma unroll
        for (int rt = 0; rt < 4; rt++) {
            int m = rowb + rowg + rt * 16 + l15;
            af[rt] = *reinterpret_cast<const bf16x8*>(x + (size_t)m * 512 + c * 32 + quad * 8);
        }
        bf16x8 bw[4];
#pragma unroll
        for (int ct = 0; ct < 4; ct++)
            bw[ct] = *reinterpret_cast<const bf16x8*>(
                sW + cb + (colg + ct * 16 + l15) * 32 + (quad ^ swz) * 8);
#pragma unroll
        for (int ct = 0; ct < 4; ct++)
#pragma unroll
            for (int rt = 0; rt < 4; rt++)
                acc[rt][ct] = __builtin_amdgcn_mfma_f32_16x16x32_bf16(af[rt], bw[ct], acc[rt][ct], 0, 0, 0);
        __syncthreads();
    }

#pragma unroll
    for (int ct = 0; ct < 4; ct++) {
        int n = colb + colg + ct * 16 + l15;
        float bias = pb[n];
#pragma unroll
        for (int rt = 0; rt < 4; rt++)
#pragma unroll
            for (int r = 0; r < 4; r++) {
                int m = rowb + rowg + rt * 16 + quad * 4 + r;
                float v = acc[rt][ct][r] + bias;
                if (F32) ((float*)out)[(size_t)m * 512 + n] = v;
                else     ((ushort_t*)out)[(size_t)m * 512 + n] = f2bf(v);
            }
    }
}
__global__ __launch_bounds__(512, 4) void kproj(const int* __restrict__ dt, const ushort_t* __restrict__ x,
                                                const ushort_t* __restrict__ proj_wt,
                                                const float* __restrict__ pb, void* __restrict__ out) {
    __shared__ ushort_t sW[2 * 128 * 32];
    if (dt[0]) kproj_body<false>(x, proj_wt, pb, out, sW);
    else       kproj_body<true>(x, proj_wt, pb, out, sW);
}

extern "C" void kernel_launch(void* const* d_in, const int* in_sizes, int n_in,
                              void* d_out, int out_size, void* d_ws, size_t ws_size,
                              hipStream_t stream) {
    (void)in_sizes; (void)n_in; (void)out_size;
    const void* pos    = d_in[0];
    const void* feat   = d_in[1];
    const void* qkv_w  = d_in[2];
    const void* qkv_b  = d_in[3];
    const void* pos_w  = d_in[4];
    // d_in[5] = pos_b: softmax-invariant (constant per attention row), intentionally unused
    const void* proj_w = d_in[6];
    const void* proj_b = d_in[7];
    const int* mask    = (const int*)d_in[8];

    char* ws = (char*)d_ws;
    int* pmax         = (int*)ws;                           // ints 0,1
    int* dtf          = (int*)ws + 2;                       // int 2: dtype flag
    float* qb         = (float*)(ws + 256);                 // 1536 f32
    float* pb         = (float*)(ws + 256 + 6144);          // 512 f32
    float* tb         = (float*)(ws + 16384);               // 65536*8 f32 = 2 MB
    ushort_t* qkv_wt  = (ushort_t*)(ws + 16384 + 2097152);  // 1536x512 bf16
    ushort_t* proj_wt = qkv_wt + 786432;                    // 512x512 bf16
    ushort_t* x       = proj_wt + 262144;                   // 65536x512 bf16 = 64 MB
    ushort_t* featb   = x + 33554432;                       // 65536x512 bf16 = 64 MB
    const size_t NEED = 16384 + 2097152 + 1572864 + 524288 + 67108864 + 67108864;
    const bool big = ws_size >= NEED;

    (void)hipMemsetAsync(ws, 0, 16, stream);
    kprobe<<<1, 64, 0, stream>>>((const ushort_t*)pos, dtf);
    kpos_max<<<256, 256, 0, stream>>>(dtf, pos, pmax);
    ktb<<<256, 256, 0, stream>>>(dtf, pos, pos_w, mask, pmax, tb);
    kbias<<<6, 256, 0, stream>>>(dtf, qkv_b, proj_b, qb, pb);
    ktrans<<<192, 256, 0, stream>>>(dtf, qkv_w, qkv_wt, 512, 1536);
    ktrans<<<64, 256, 0, stream>>>(dtf, proj_w, proj_wt, 512, 512);
    if (big) {
        kfeat<<<2048, 256, 0, stream>>>(dtf, feat, featb);
        kattn_bf<<<2048, 512, 0, stream>>>(featb, qkv_wt, qb, tb, x);
    } else {
        kattn_dyn<<<2048, 512, 0, stream>>>(dtf, feat, qkv_wt, qb, tb, x);
    }
    kproj<<<1024, 512, 0, stream>>>(dtf, x, proj_wt, pb, d_out);
}

// Round 6
// 594.323 us; speedup vs baseline: 1.2574x; 1.2574x over previous
//
#include <hip/hip_runtime.h>
#include <stdint.h>

typedef short bf16x8 __attribute__((ext_vector_type(8)));
typedef float f32x4 __attribute__((ext_vector_type(4)));
typedef unsigned short u16x4 __attribute__((ext_vector_type(4)));
typedef unsigned short ushort_t;

__device__ __forceinline__ float bf2f(unsigned short u) {
    union { unsigned int i; float f; } v; v.i = ((unsigned int)u) << 16; return v.f;
}
__device__ __forceinline__ unsigned short f2bf(float f) {
    union { float f; unsigned int i; } v; v.f = f;
    unsigned int r = (v.i + 0x7FFFu + ((v.i >> 16) & 1u)) >> 16;
    return (unsigned short)r;
}

// async global->LDS, 16B per lane; LDS dest = wave-uniform base + lane*16
__device__ __forceinline__ void gload_lds16(const void* g, void* l) {
    __builtin_amdgcn_global_load_lds(
        (const __attribute__((address_space(1))) void*)g,
        (__attribute__((address_space(3))) void*)l, 16, 0, 0);
}

// Dtype-polymorphic loaders. F32=true: buffers are float32. F32=false: bf16.
template <bool F32> struct LD;
template <> struct LD<false> {
    static __device__ __forceinline__ float s(const void* p, size_t i) {
        return bf2f(((const ushort_t*)p)[i]);
    }
    static __device__ __forceinline__ bf16x8 v8(const void* p, size_t i) {
        return *reinterpret_cast<const bf16x8*>((const ushort_t*)p + i);
    }
};
template <> struct LD<true> {
    static __device__ __forceinline__ float s(const void* p, size_t i) {
        return ((const float*)p)[i];
    }
    static __device__ __forceinline__ bf16x8 v8(const void* p, size_t i) {
        const float* f = (const float*)p + i;
        float4 a = *reinterpret_cast<const float4*>(f);
        float4 b = *reinterpret_cast<const float4*>(f + 4);
        bf16x8 r;
        r[0] = (short)f2bf(a.x); r[1] = (short)f2bf(a.y);
        r[2] = (short)f2bf(a.z); r[3] = (short)f2bf(a.w);
        r[4] = (short)f2bf(b.x); r[5] = (short)f2bf(b.y);
        r[6] = (short)f2bf(b.z); r[7] = (short)f2bf(b.w);
        return r;
    }
};

// ---------------- K0: dtype probe ----------------
__global__ __launch_bounds__(64) void kprobe(const ushort_t* __restrict__ pos, int* __restrict__ dt) {
    float v = bf2f(pos[2 * threadIdx.x]);
    bool sane = (v >= 0.0f) && (v <= 1.0f);
    unsigned long long b = __ballot(sane);
    if (threadIdx.x == 0) dt[0] = (b == ~0ULL) ? 1 : 0;  // 1 = bf16, 0 = f32
}

// ---------------- K1: global max of pos per coordinate ----------------
template <bool F32>
static __device__ __forceinline__ void kpos_body(const void* pos, int* pmax, float* s0, float* s1) {
    int p = blockIdx.x * 256 + threadIdx.x;
    s0[threadIdx.x] = LD<F32>::s(pos, 2 * (size_t)p);
    s1[threadIdx.x] = LD<F32>::s(pos, 2 * (size_t)p + 1);
    __syncthreads();
    for (int off = 128; off > 0; off >>= 1) {
        if (threadIdx.x < (unsigned)off) {
            s0[threadIdx.x] = fmaxf(s0[threadIdx.x], s0[threadIdx.x + off]);
            s1[threadIdx.x] = fmaxf(s1[threadIdx.x], s1[threadIdx.x + off]);
        }
        __syncthreads();
    }
    if (threadIdx.x == 0) {
        atomicMax(&pmax[0], __float_as_int(s0[0]));
        atomicMax(&pmax[1], __float_as_int(s1[0]));
    }
}
__global__ __launch_bounds__(256) void kpos_max(const int* __restrict__ dt, const void* __restrict__ pos,
                                                int* __restrict__ pmax) {
    __shared__ float s0[256], s1[256];
    if (dt[0]) kpos_body<false>(pos, pmax, s0, s1);
    else       kpos_body<true>(pos, pmax, s0, s1);
}

// ---------------- K2: per-key bias tb[p][h] = pos_n . pos_w + maskterm ----------------
template <bool F32>
static __device__ __forceinline__ void ktb_body(const void* pos, const void* pos_w, const int* mask,
                                                const int* pmax, float* tb) {
    int p = blockIdx.x * 256 + threadIdx.x;
    float inv0 = 1.0f / __int_as_float(pmax[0]);
    float inv1 = 1.0f / __int_as_float(pmax[1]);
    float x0 = LD<F32>::s(pos, 2 * (size_t)p) * inv0;
    float x1 = LD<F32>::s(pos, 2 * (size_t)p + 1) * inv1;
    float mterm = mask[p] ? 0.0f : -100.0f;
#pragma unroll
    for (int h = 0; h < 8; h++)
        tb[p * 8 + h] = x0 * LD<F32>::s(pos_w, h) + x1 * LD<F32>::s(pos_w, 8 + h) + mterm;
}
__global__ __launch_bounds__(256) void ktb(const int* __restrict__ dt, const void* __restrict__ pos,
                                           const void* __restrict__ pos_w, const int* __restrict__ mask,
                                           const int* __restrict__ pmax, float* __restrict__ tb) {
    if (dt[0]) ktb_body<false>(pos, pos_w, mask, pmax, tb);
    else       ktb_body<true>(pos, pos_w, mask, pmax, tb);
}

// ---------------- Kb: biases -> f32 ----------------
__global__ __launch_bounds__(256) void kbias(const int* __restrict__ dt, const void* __restrict__ qkv_b,
                                             const void* __restrict__ proj_b,
                                             float* __restrict__ qb, float* __restrict__ pb) {
    int i = blockIdx.x * 256 + threadIdx.x;
    if (dt[0]) {
        if (i < 1536) qb[i] = bf2f(((const ushort_t*)qkv_b)[i]);
        if (i < 512)  pb[i] = bf2f(((const ushort_t*)proj_b)[i]);
    } else {
        if (i < 1536) qb[i] = ((const float*)qkv_b)[i];
        if (i < 512)  pb[i] = ((const float*)proj_b)[i];
    }
}

// ---------------- Kf: feat -> bf16 once ----------------
template <bool F32>
static __device__ __forceinline__ void kfeat_body(const void* feat, ushort_t* featb) {
    for (size_t t = (size_t)blockIdx.x * 256 + threadIdx.x; t < 4194304; t += (size_t)gridDim.x * 256) {
        *reinterpret_cast<bf16x8*>(featb + t * 8) = LD<F32>::v8(feat, t * 8);
    }
}
__global__ __launch_bounds__(256) void kfeat(const int* __restrict__ dt, const void* __restrict__ feat,
                                             ushort_t* __restrict__ featb) {
    if (dt[0]) kfeat_body<false>(feat, featb);
    else       kfeat_body<true>(feat, featb);
}

// ---------------- Kt: transpose (R x C -> C x R) into bf16, 64x64 tiles ----------------
template <bool F32>
static __device__ __forceinline__ void ktrans_body(const void* src, ushort_t* dst, int R, int C,
                                                   ushort_t* tile /*64x65*/) {
    int nbc = C >> 6;
    int rb = (blockIdx.x / nbc) << 6;
    int cb = (blockIdx.x % nbc) << 6;
    for (int i = threadIdx.x; i < 4096; i += 256) {
        int r = i >> 6, c = i & 63;
        tile[r * 65 + c] = f2bf(LD<F32>::s(src, (size_t)(rb + r) * C + cb + c));
    }
    __syncthreads();
    for (int i = threadIdx.x; i < 4096; i += 256) {
        int rr = i & 63, cc = i >> 6;
        dst[(size_t)(cb + cc) * R + rb + rr] = tile[rr * 65 + cc];
    }
}
__global__ __launch_bounds__(256) void ktrans(const int* __restrict__ dt, const void* __restrict__ src,
                                              ushort_t* __restrict__ dst, int R, int C) {
    __shared__ ushort_t tile[64 * 65];
    if (dt[0]) ktrans_body<false>(src, dst, R, C, tile);
    else       ktrans_body<true>(src, dst, R, C, tile);
}

// ---------------- K3: fused QKV projection + attention ----------------
// R2 skeleton (best measured: 256us) with K-chunk widened 32->64:
// 8 barrier-coupled iterations instead of 16; each stages 24KB of W
// (192 rows x 64 cols, dbuf 2x24KB aliased on the c-loop-dead sQ/sK
// region) and runs 48 MFMA/wave. Staging is task-linear (3 gload_lds16
// per thread) with source-side chunk XOR (ch ^= row&7) so stride-128B
// ds_read_b128 spreads across all banks. Phase B identical to R2.
template <bool F32>
static __device__ __forceinline__ void kattn_body(const void* feat, const ushort_t* qkv_wt,
                                                  const float* qb, const float* tb, ushort_t* xout,
                                                  ushort_t* smem) {
    const int tid = threadIdx.x;
    const int lane = tid & 63;
    const int wave = tid >> 6;   // 0..7
    const int quad = lane >> 4;
    const int l15 = lane & 15;

    // XCD-aware decode: all 8 heads of a cluster co-resident on one XCD round
    const int bx = blockIdx.x;
    const int xcd = bx & 7;
    const int jj = bx >> 3;
    const int rr = jj >> 5;
    const int ss = jj & 31;
    const int kc = xcd * 32 + rr * 4 + (ss >> 3);
    const int h = ss & 7;

    // LDS carve (u16 idx): sQ[0,18432) sK[18432,36864) sVt[36864,53760)
    //                      sP[53760,72192) stb(float) at [72192,72704)
    ushort_t* sQ  = smem;
    ushort_t* sK  = smem + 18432;
    ushort_t* sVt = smem + 36864;   // [64][264]
    ushort_t* sP  = smem + 53760;   // 8 waves x 32 x 72
    float*    stb = (float*)(smem + 72192);
    char*     stg = (char*)smem;    // W staging [0,49152)B over sQ+sK (dead in c-loop)

    if (tid < 256) stb[tid] = tb[(size_t)(kc * 256 + tid) * 8 + h];

    // staging tasks: 1536 = 192 rows x 8 chunks(16B); 3 per thread, source chunk XOR'd
    const int t0 = tid, t1 = tid + 512, t2 = tid + 1024;
    const int r0 = t0 >> 3, r1 = t1 >> 3, r2 = t2 >> 3;
    const ushort_t* g0 = qkv_wt + (size_t)((r0 >> 6) * 512 + h * 64 + (r0 & 63)) * 512 + (((t0 & 7) ^ (r0 & 7)) * 8);
    const ushort_t* g1 = qkv_wt + (size_t)((r1 >> 6) * 512 + h * 64 + (r1 & 63)) * 512 + (((t1 & 7) ^ (r1 & 7)) * 8);
    const ushort_t* g2 = qkv_wt + (size_t)((r2 >> 6) * 512 + h * 64 + (r2 & 63)) * 512 + (((t2 & 7) ^ (r2 & 7)) * 8);

    const int wrow = (wave >> 1) * 64;   // 4 row groups
    const int wcol = (wave & 1) * 96;    // 2 col groups (of 192 = 3 mats x 64)

    f32x4 acc[4][6];
#pragma unroll
    for (int rt = 0; rt < 4; rt++)
#pragma unroll
        for (int ct = 0; ct < 6; ct++) {
            f32x4 z = {0.0f, 0.0f, 0.0f, 0.0f};
            acc[rt][ct] = z;
        }

    const size_t fbase = (size_t)(kc * 256) * 512;

    // prologue: stage K-chunk 0 into buf0
    gload_lds16(g0, stg + t0 * 16);
    gload_lds16(g1, stg + t1 * 16);
    gload_lds16(g2, stg + t2 * 16);
    __syncthreads();

#pragma unroll 2
    for (int it = 0; it < 8; it++) {
        if (it < 7) {
            const int nb = ((it + 1) & 1) * 24576;
            gload_lds16(g0 + (it + 1) * 64, stg + nb + t0 * 16);
            gload_lds16(g1 + (it + 1) * 64, stg + nb + t1 * 16);
            gload_lds16(g2 + (it + 1) * 64, stg + nb + t2 * 16);
        }
        const int cbu = (it & 1) * 12288;  // u16 offset of current buf
#pragma unroll
        for (int s = 0; s < 2; s++) {
            bf16x8 af[4];
#pragma unroll
            for (int rt = 0; rt < 4; rt++)
                af[rt] = LD<F32>::v8(
                    feat, fbase + (size_t)(wrow + rt * 16 + l15) * 512 + it * 64 + s * 32 + quad * 8);
            bf16x8 bw[6];
#pragma unroll
            for (int ct = 0; ct < 6; ct++) {
                const int rw = wcol + ct * 16 + l15;
                bw[ct] = *reinterpret_cast<const bf16x8*>(
                    smem + cbu + rw * 64 + (((s * 4 + quad) ^ (rw & 7)) * 8));
            }
#pragma unroll
            for (int ct = 0; ct < 6; ct++)
#pragma unroll
                for (int rt = 0; rt < 4; rt++)
                    acc[rt][ct] = __builtin_amdgcn_mfma_f32_16x16x32_bf16(af[rt], bw[ct], acc[rt][ct], 0, 0, 0);
        }
        __syncthreads();
    }

    // Epilogue: bias, scale Q, store Q/K row-major and V transposed into LDS
#pragma unroll
    for (int ct = 0; ct < 6; ct++) {
        const int lcb = wcol + ct * 16;      // 16-aligned segment within [0,192)
        const int mat = lcb >> 6;            // wave-uniform: 0=Q 1=K 2=V
        const int col = (lcb & 63) + l15;    // 0..63
        const float bias = qb[mat * 512 + h * 64 + col];
#pragma unroll
        for (int rt = 0; rt < 4; rt++) {
            const int m0 = wrow + rt * 16 + quad * 4;
            if (mat == 0) {
#pragma unroll
                for (int r = 0; r < 4; r++)
                    sQ[(m0 + r) * 72 + col] = f2bf((acc[rt][ct][r] + bias) * 0.125f);
            } else if (mat == 1) {
#pragma unroll
                for (int r = 0; r < 4; r++)
                    sK[(m0 + r) * 72 + col] = f2bf(acc[rt][ct][r] + bias);
            } else {
                u16x4 vp;
#pragma unroll
                for (int r = 0; r < 4; r++) vp[r] = f2bf(acc[rt][ct][r] + bias);
                *reinterpret_cast<u16x4*>(&sVt[col * 264 + m0]) = vp;
            }
        }
    }
    __syncthreads();

    // ---- Phase B: S = Q K^T + bias, exp, P@V, normalize (unchanged from R2) ----
    bf16x8 aQ[2][2];
#pragma unroll
    for (int rt = 0; rt < 2; rt++)
#pragma unroll
        for (int s = 0; s < 2; s++)
            aQ[rt][s] = *reinterpret_cast<const bf16x8*>(
                &sQ[(wave * 32 + rt * 16 + l15) * 72 + s * 32 + quad * 8]);

    f32x4 accO[2][4];
    float rs[2][4];
#pragma unroll
    for (int rt = 0; rt < 2; rt++)
#pragma unroll
        for (int ct = 0; ct < 4; ct++) {
            f32x4 z = {0.0f, 0.0f, 0.0f, 0.0f};
            accO[rt][ct] = z;
            rs[rt][ct] = 0.0f;  // rs[rt][r]
        }

    ushort_t* sPw = sP + wave * (32 * 72);

    for (int jb = 0; jb < 4; jb++) {
        int kb = jb * 64;
        bf16x8 bK[4][2];
#pragma unroll
        for (int ctk = 0; ctk < 4; ctk++)
#pragma unroll
            for (int s = 0; s < 2; s++)
                bK[ctk][s] = *reinterpret_cast<const bf16x8*>(
                    &sK[(kb + ctk * 16 + l15) * 72 + s * 32 + quad * 8]);

#pragma unroll
        for (int ctk = 0; ctk < 4; ctk++) {
            float tcol = stb[kb + ctk * 16 + l15];
#pragma unroll
            for (int rt = 0; rt < 2; rt++) {
                f32x4 sa = {0.0f, 0.0f, 0.0f, 0.0f};
                sa = __builtin_amdgcn_mfma_f32_16x16x32_bf16(aQ[rt][0], bK[ctk][0], sa, 0, 0, 0);
                sa = __builtin_amdgcn_mfma_f32_16x16x32_bf16(aQ[rt][1], bK[ctk][1], sa, 0, 0, 0);
                int rl0 = rt * 16 + quad * 4;
#pragma unroll
                for (int r = 0; r < 4; r++) {
                    float pexp = __expf(sa[r] + tcol);  // |S|<~5, masked ~ -100, safe in f32
                    rs[rt][r] += pexp;
                    sPw[(rl0 + r) * 72 + ctk * 16 + l15] = f2bf(pexp);
                }
            }
        }

        // P @ V over this key block (wave-private P, same-wave LDS ordering, no barrier)
#pragma unroll
        for (int s = 0; s < 2; s++) {
            bf16x8 aP[2];
#pragma unroll
            for (int rt = 0; rt < 2; rt++)
                aP[rt] = *reinterpret_cast<const bf16x8*>(
                    &sPw[(rt * 16 + l15) * 72 + s * 32 + quad * 8]);
#pragma unroll
            for (int ct = 0; ct < 4; ct++) {
                bf16x8 bV = *reinterpret_cast<const bf16x8*>(
                    &sVt[(ct * 16 + l15) * 264 + kb + s * 32 + quad * 8]);
#pragma unroll
                for (int rt = 0; rt < 2; rt++)
                    accO[rt][ct] =
                        __builtin_amdgcn_mfma_f32_16x16x32_bf16(aP[rt], bV, accO[rt][ct], 0, 0, 0);
            }
        }
    }

    // Row sums: butterfly over the 16 lanes sharing a quad
    float inv_[2][4];
#pragma unroll
    for (int rt = 0; rt < 2; rt++)
#pragma unroll
        for (int r = 0; r < 4; r++) {
            float v = rs[rt][r];
            v += __shfl_xor(v, 1, 64);
            v += __shfl_xor(v, 2, 64);
            v += __shfl_xor(v, 4, 64);
            v += __shfl_xor(v, 8, 64);
            inv_[rt][r] = 1.0f / v;
        }

#pragma unroll
    for (int rt = 0; rt < 2; rt++)
#pragma unroll
        for (int ct = 0; ct < 4; ct++)
#pragma unroll
            for (int r = 0; r < 4; r++) {
                int m = wave * 32 + rt * 16 + quad * 4 + r;
                xout[((size_t)(kc * 256 + m)) * 512 + h * 64 + ct * 16 + l15] =
                    f2bf(accO[rt][ct][r] * inv_[rt][r]);
            }
}
__global__ __launch_bounds__(512, 2) void kattn_bf(const ushort_t* __restrict__ featb,
                                                   const ushort_t* __restrict__ qkv_wt,
                                                   const float* __restrict__ qb,
                                                   const float* __restrict__ tb, ushort_t* __restrict__ xout) {
    __shared__ ushort_t smem[72704];  // 145408 B, same as R2
    kattn_body<false>(featb, qkv_wt, qb, tb, xout, smem);
}
__global__ __launch_bounds__(512, 2) void kattn_dyn(const int* __restrict__ dt, const void* __restrict__ feat,
                                                    const ushort_t* __restrict__ qkv_wt,
                                                    const float* __restrict__ qb,
                                                    const float* __restrict__ tb, ushort_t* __restrict__ xout) {
    __shared__ ushort_t smem[72704];
    if (dt[0]) kattn_body<false>(feat, qkv_wt, qb, tb, xout, smem);
    else       kattn_body<true>(feat, qkv_wt, qb, tb, xout, smem);
}

// ---------------- K4: out = x @ proj_w + proj_b ----------------
// 512 threads (8 waves), tile 256x128, K-chunk 64: 8 iterations, each
// staging 16KB of W (dbuf 2x16KB = 32KB LDS -> 2 blocks/CU), 32 MFMA/wave
// per barrier. Task-linear staging + source chunk XOR as in kattn.
template <bool F32>
static __device__ __forceinline__ void kproj_body(const ushort_t* x, const ushort_t* proj_wt,
                                                  const float* pb, void* out, ushort_t* sW) {
    const int tid = threadIdx.x;
    const int lane = tid & 63;
    const int wave = tid >> 6;   // 0..7
    const int quad = lane >> 4;
    const int l15 = lane & 15;
    const int bx = blockIdx.x;
    const int xcd = bx & 7;
    const int j = bx >> 3;                           // 0..127
    const int rowb = (xcd * 32 + (j >> 2)) * 256;    // 256-row panel
    const int colb = (j & 3) * 128;                  // 128-col block
    const int rowg = (wave >> 1) * 64;
    const int colg = (wave & 1) * 64;
    char* stg = (char*)sW;

    // staging: 1024 tasks = 128 rows x 8 chunks(16B); 2 per thread, source chunk XOR'd
    const int t0 = tid, t1 = tid + 512;
    const int r0 = t0 >> 3, r1 = t1 >> 3;
    const ushort_t* g0 = proj_wt + (size_t)(colb + r0) * 512 + (((t0 & 7) ^ (r0 & 7)) * 8);
    const ushort_t* g1 = proj_wt + (size_t)(colb + r1) * 512 + (((t1 & 7) ^ (r1 & 7)) * 8);

    f32x4 acc[4][4];
#pragma unroll
    for (int rt = 0; rt < 4; rt++)
#pragma unroll
        for (int ct = 0; ct < 4; ct++) {
            f32x4 z = {0.0f, 0.0f, 0.0f, 0.0f};
            acc[rt][ct] = z;
        }

    gload_lds16(g0, stg + t0 * 16);
    gload_lds16(g1, stg + t1 * 16);
    __syncthreads();

#pragma unroll 2
    for (int it = 0; it < 8; it++) {
        if (it < 7) {
            const int nb = ((it + 1) & 1) * 16384;
            gload_lds16(g0 + (it + 1) * 64, stg + nb + t0 * 16);
            gload_lds16(g1 + (it + 1) * 64, stg + nb + t1 * 16);
        }
        const int cbu = (it & 1) * 8192;  // u16 offset of current buf
#pragma unroll
        for (int s = 0; s < 2; s++) {
            bf16x8 af[4];
#pragma unroll
            for (int rt = 0; rt < 4; rt++) {
                int m = rowb + rowg + rt * 16 + l15;
                af[rt] = *reinterpret_cast<const bf16x8*>(
                    x + (size_t)m * 512 + it * 64 + s * 32 + quad * 8);
            }
            bf16x8 bw[4];
#pragma unroll
            for (int ct = 0; ct < 4; ct++) {
                const int rw = colg + ct * 16 + l15;
                bw[ct] = *reinterpret_cast<const bf16x8*>(
                    sW + cbu + rw * 64 + (((s * 4 + quad) ^ (rw & 7)) * 8));
            }
#pragma unroll
            for (int ct = 0; ct < 4; ct++)
#pragma unroll
                for (int rt = 0; rt < 4; rt++)
                    acc[rt][ct] = __builtin_amdgcn_mfma_f32_16x16x32_bf16(af[rt], bw[ct], acc[rt][ct], 0, 0, 0);
        }
        __syncthreads();
    }

#pragma unroll
    for (int ct = 0; ct < 4; ct++) {
        int n = colb + colg + ct * 16 + l15;
        float bias = pb[n];
#pragma unroll
        for (int rt = 0; rt < 4; rt++)
#pragma unroll
            for (int r = 0; r < 4; r++) {
                int m = rowb + rowg + rt * 16 + quad * 4 + r;
                float v = acc[rt][ct][r] + bias;
                if (F32) ((float*)out)[(size_t)m * 512 + n] = v;
                else     ((ushort_t*)out)[(size_t)m * 512 + n] = f2bf(v);
            }
    }
}
__global__ __launch_bounds__(512, 4) void kproj(const int* __restrict__ dt, const ushort_t* __restrict__ x,
                                                const ushort_t* __restrict__ proj_wt,
                                                const float* __restrict__ pb, void* __restrict__ out) {
    __shared__ ushort_t sW[16384];  // 32768 B -> 2 blocks/CU
    if (dt[0]) kproj_body<false>(x, proj_wt, pb, out, sW);
    else       kproj_body<true>(x, proj_wt, pb, out, sW);
}

extern "C" void kernel_launch(void* const* d_in, const int* in_sizes, int n_in,
                              void* d_out, int out_size, void* d_ws, size_t ws_size,
                              hipStream_t stream) {
    (void)in_sizes; (void)n_in; (void)out_size;
    const void* pos    = d_in[0];
    const void* feat   = d_in[1];
    const void* qkv_w  = d_in[2];
    const void* qkv_b  = d_in[3];
    const void* pos_w  = d_in[4];
    // d_in[5] = pos_b: softmax-invariant (constant per attention row), intentionally unused
    const void* proj_w = d_in[6];
    const void* proj_b = d_in[7];
    const int* mask    = (const int*)d_in[8];

    char* ws = (char*)d_ws;
    int* pmax         = (int*)ws;                           // ints 0,1
    int* dtf          = (int*)ws + 2;                       // int 2: dtype flag
    float* qb         = (float*)(ws + 256);                 // 1536 f32
    float* pb         = (float*)(ws + 256 + 6144);          // 512 f32
    float* tb         = (float*)(ws + 16384);               // 65536*8 f32 = 2 MB
    ushort_t* qkv_wt  = (ushort_t*)(ws + 16384 + 2097152);  // 1536x512 bf16
    ushort_t* proj_wt = qkv_wt + 786432;                    // 512x512 bf16
    ushort_t* x       = proj_wt + 262144;                   // 65536x512 bf16 = 64 MB
    ushort_t* featb   = x + 33554432;                       // 65536x512 bf16 = 64 MB
    const size_t NEED = 16384 + 2097152 + 1572864 + 524288 + 67108864 + 67108864;
    const bool big = ws_size >= NEED;

    (void)hipMemsetAsync(ws, 0, 16, stream);
    kprobe<<<1, 64, 0, stream>>>((const ushort_t*)pos, dtf);
    kpos_max<<<256, 256, 0, stream>>>(dtf, pos, pmax);
    ktb<<<256, 256, 0, stream>>>(dtf, pos, pos_w, mask, pmax, tb);
    kbias<<<6, 256, 0, stream>>>(dtf, qkv_b, proj_b, qb, pb);
    ktrans<<<192, 256, 0, stream>>>(dtf, qkv_w, qkv_wt, 512, 1536);
    ktrans<<<64, 256, 0, stream>>>(dtf, proj_w, proj_wt, 512, 512);
    if (big) {
        kfeat<<<2048, 256, 0, stream>>>(dtf, feat, featb);
        kattn_bf<<<2048, 512, 0, stream>>>(featb, qkv_wt, qb, tb, x);
    } else {
        kattn_dyn<<<2048, 512, 0, stream>>>(dtf, feat, qkv_wt, qb, tb, x);
    }
    kproj<<<1024, 512, 0, stream>>>(dtf, x, proj_wt, pb, d_out);
}

// Round 7
// 557.236 us; speedup vs baseline: 1.3411x; 1.0666x over previous
//
#include <hip/hip_runtime.h>
#include <stdint.h>

typedef short bf16x8 __attribute__((ext_vector_type(8)));
typedef float f32x4 __attribute__((ext_vector_type(4)));
typedef unsigned short u16x4 __attribute__((ext_vector_type(4)));
typedef unsigned short ushort_t;

__device__ __forceinline__ float bf2f(unsigned short u) {
    union { unsigned int i; float f; } v; v.i = ((unsigned int)u) << 16; return v.f;
}
__device__ __forceinline__ unsigned short f2bf(float f) {
    union { float f; unsigned int i; } v; v.f = f;
    unsigned int r = (v.i + 0x7FFFu + ((v.i >> 16) & 1u)) >> 16;
    return (unsigned short)r;
}

// async global->LDS, 16B per lane; LDS dest = wave-uniform base + lane*16
__device__ __forceinline__ void gload_lds16(const void* g, void* l) {
    __builtin_amdgcn_global_load_lds(
        (const __attribute__((address_space(1))) void*)g,
        (__attribute__((address_space(3))) void*)l, 16, 0, 0);
}

// Dtype-polymorphic loaders. F32=true: buffers are float32. F32=false: bf16.
template <bool F32> struct LD;
template <> struct LD<false> {
    static __device__ __forceinline__ float s(const void* p, size_t i) {
        return bf2f(((const ushort_t*)p)[i]);
    }
    static __device__ __forceinline__ bf16x8 v8(const void* p, size_t i) {
        return *reinterpret_cast<const bf16x8*>((const ushort_t*)p + i);
    }
};
template <> struct LD<true> {
    static __device__ __forceinline__ float s(const void* p, size_t i) {
        return ((const float*)p)[i];
    }
    static __device__ __forceinline__ bf16x8 v8(const void* p, size_t i) {
        const float* f = (const float*)p + i;
        float4 a = *reinterpret_cast<const float4*>(f);
        float4 b = *reinterpret_cast<const float4*>(f + 4);
        bf16x8 r;
        r[0] = (short)f2bf(a.x); r[1] = (short)f2bf(a.y);
        r[2] = (short)f2bf(a.z); r[3] = (short)f2bf(a.w);
        r[4] = (short)f2bf(b.x); r[5] = (short)f2bf(b.y);
        r[6] = (short)f2bf(b.z); r[7] = (short)f2bf(b.w);
        return r;
    }
};

// ---------------- prep helpers (device) ----------------
template <bool F32>
static __device__ __forceinline__ void ktrans_body(const void* src, ushort_t* dst, int R, int C,
                                                   ushort_t* tile /*64x65*/, int bx) {
    int nbc = C >> 6;
    int rb = (bx / nbc) << 6;
    int cb = (bx % nbc) << 6;
    for (int i = threadIdx.x; i < 4096; i += 256) {
        int r = i >> 6, c = i & 63;
        tile[r * 65 + c] = f2bf(LD<F32>::s(src, (size_t)(rb + r) * C + cb + c));
    }
    __syncthreads();
    for (int i = threadIdx.x; i < 4096; i += 256) {
        int rr = i & 63, cc = i >> 6;
        dst[(size_t)(cb + cc) * R + rb + rr] = tile[rr * 65 + cc];
    }
}

template <bool F32>
static __device__ __forceinline__ void kpos_body(const void* pos, int* pmax, float* s0, float* s1, int bx) {
    int p = bx * 256 + threadIdx.x;
    s0[threadIdx.x] = LD<F32>::s(pos, 2 * (size_t)p);
    s1[threadIdx.x] = LD<F32>::s(pos, 2 * (size_t)p + 1);
    __syncthreads();
    for (int off = 128; off > 0; off >>= 1) {
        if (threadIdx.x < (unsigned)off) {
            s0[threadIdx.x] = fmaxf(s0[threadIdx.x], s0[threadIdx.x + off]);
            s1[threadIdx.x] = fmaxf(s1[threadIdx.x], s1[threadIdx.x + off]);
        }
        __syncthreads();
    }
    if (threadIdx.x == 0) {
        atomicMax(&pmax[0], __float_as_int(s0[0]));
        atomicMax(&pmax[1], __float_as_int(s1[0]));
    }
}

// ---------------- Kprep: ALL preprocessing in ONE dispatch ----------------
// Block roles: [0,192) qkv_w transpose | [192,256) proj_w transpose |
// [256,512) pos global max | 512 bias conversion (+dtf publish) |
// [513,2561) feat -> bf16 (big-workspace path only; grid shrunk otherwise).
// Dtype is probed locally per block (64 ushort reads of pos, L2-hot).
__global__ __launch_bounds__(256) void kprep(const void* __restrict__ pos, const void* __restrict__ feat,
                                             const void* __restrict__ qkv_w, const void* __restrict__ proj_w,
                                             const void* __restrict__ qkv_b, const void* __restrict__ proj_b,
                                             int* __restrict__ pmax, int* __restrict__ dtf,
                                             float* __restrict__ qb, float* __restrict__ pb,
                                             ushort_t* __restrict__ featb,
                                             ushort_t* __restrict__ qkv_wt, ushort_t* __restrict__ proj_wt) {
    __shared__ char smem[8448];   // max(64*65 u16 = 8320B, 2*256 f32 = 2048B)
    __shared__ int sdt;
    const int tid = threadIdx.x;
    if (tid < 64) {
        float v = bf2f(((const ushort_t*)pos)[2 * tid]);
        bool sane = (v >= 0.0f) && (v <= 1.0f);
        unsigned long long b = __ballot(sane);
        if (tid == 0) sdt = (b == ~0ULL) ? 1 : 0;   // 1 = bf16, 0 = f32
    }
    __syncthreads();
    const bool isbf = (sdt != 0);
    const int bx = blockIdx.x;

    if (bx < 192) {
        ushort_t* tile = (ushort_t*)smem;
        if (isbf) ktrans_body<false>(qkv_w, qkv_wt, 512, 1536, tile, bx);
        else      ktrans_body<true>(qkv_w, qkv_wt, 512, 1536, tile, bx);
    } else if (bx < 256) {
        ushort_t* tile = (ushort_t*)smem;
        if (isbf) ktrans_body<false>(proj_w, proj_wt, 512, 512, tile, bx - 192);
        else      ktrans_body<true>(proj_w, proj_wt, 512, 512, tile, bx - 192);
    } else if (bx < 512) {
        float* s0 = (float*)smem;
        float* s1 = s0 + 256;
        if (isbf) kpos_body<false>(pos, pmax, s0, s1, bx - 256);
        else      kpos_body<true>(pos, pmax, s0, s1, bx - 256);
    } else if (bx == 512) {
        if (tid == 0) dtf[0] = isbf ? 1 : 0;
        for (int i = tid; i < 1536; i += 256)
            qb[i] = isbf ? bf2f(((const ushort_t*)qkv_b)[i]) : ((const float*)qkv_b)[i];
        for (int i = tid; i < 512; i += 256)
            pb[i] = isbf ? bf2f(((const ushort_t*)proj_b)[i]) : ((const float*)proj_b)[i];
    } else {
        const int fb = bx - 513;   // 0..2047
        if (isbf) {
#pragma unroll
            for (int i = 0; i < 8; i++) {
                size_t t = (size_t)fb * 256 + tid + (size_t)i * 524288;
                *reinterpret_cast<bf16x8*>(featb + t * 8) = LD<false>::v8(feat, t * 8);
            }
        } else {
#pragma unroll
            for (int i = 0; i < 8; i++) {
                size_t t = (size_t)fb * 256 + tid + (size_t)i * 524288;
                *reinterpret_cast<bf16x8*>(featb + t * 8) = LD<true>::v8(feat, t * 8);
            }
        }
    }
}

// ---------------- K3: fused QKV projection + attention (R2-verbatim body) ----------------
// 8 waves; Phase A: qkv_wt slice staged via global_load_lds dbuf + __syncthreads
// (measured-best structure, 256us); per-key bias tb computed INLINE from
// pos/pos_w/mask/pmax (replaces the ktb kernel + 2MB buffer, bit-identical math).
template <bool F32>
static __device__ __forceinline__ void kattn_body(const void* feat, const ushort_t* qkv_wt,
                                                  const float* qb,
                                                  const void* pos, const void* pos_w,
                                                  const int* mask, const int* pmax, int dtv,
                                                  ushort_t* xout,
                                                  ushort_t* sQ, ushort_t* sK, ushort_t* sVt,
                                                  ushort_t* sP, float* stb) {
    const int tid = threadIdx.x;
    const int lane = tid & 63;
    const int wave = tid >> 6;   // 0..7
    const int quad = lane >> 4;
    const int l15 = lane & 15;

    // XCD-aware decode: all 8 heads of a cluster co-resident on one XCD round
    const int bx = blockIdx.x;
    const int xcd = bx & 7;
    const int jj = bx >> 3;
    const int rr = jj >> 5;
    const int ss = jj & 31;
    const int kc = xcd * 32 + rr * 4 + (ss >> 3);
    const int h = ss & 7;

    // inline tb: stb[p] = pos_n . pos_w[:,h] + maskterm  (identical expr to old ktb)
    if (tid < 256) {
        const int p = kc * 256 + tid;
        const float inv0 = 1.0f / __int_as_float(pmax[0]);
        const float inv1 = 1.0f / __int_as_float(pmax[1]);
        float x0, x1, w0, w1;
        if (dtv) {
            x0 = bf2f(((const ushort_t*)pos)[2 * (size_t)p]);
            x1 = bf2f(((const ushort_t*)pos)[2 * (size_t)p + 1]);
            w0 = bf2f(((const ushort_t*)pos_w)[h]);
            w1 = bf2f(((const ushort_t*)pos_w)[8 + h]);
        } else {
            x0 = ((const float*)pos)[2 * (size_t)p];
            x1 = ((const float*)pos)[2 * (size_t)p + 1];
            w0 = ((const float*)pos_w)[h];
            w1 = ((const float*)pos_w)[8 + h];
        }
        x0 *= inv0;
        x1 *= inv1;
        const float mterm = mask[p] ? 0.0f : -100.0f;
        stb[tid] = x0 * w0 + x1 * w1 + mterm;
    }

    ushort_t* sW = sP;  // Phase A W-staging aliases the (Phase-B-only) sP region
    char* ldsW = (char*)sW;

    // staging tasks: 768 = 192 rows x 4 chunks(16B). task t -> lc=t>>2, ch=t&3.
    const int t1 = wave * 64 + lane;
    const int t2 = 512 + t1;
    const int lc1 = t1 >> 2, ch1 = t1 & 3;
    const int lc2 = t2 >> 2, ch2 = t2 & 3;
    const ushort_t* g1 = qkv_wt + (size_t)((lc1 >> 6) * 512 + h * 64 + (lc1 & 63)) * 512 + ch1 * 8;
    const ushort_t* g2 = qkv_wt + (size_t)((lc2 >> 6) * 512 + h * 64 + (lc2 & 63)) * 512 + ch2 * 8;

    const int wrow = (wave >> 1) * 64;   // 4 row groups
    const int wcol = (wave & 1) * 96;    // 2 col groups (of 192 = 3 mats x 64)
    const int fcol = quad * 8;

    f32x4 acc[4][6];
#pragma unroll
    for (int rt = 0; rt < 4; rt++)
#pragma unroll
        for (int ct = 0; ct < 6; ct++) {
            f32x4 z = {0.0f, 0.0f, 0.0f, 0.0f};
            acc[rt][ct] = z;
        }

    const size_t fbase = (size_t)(kc * 256) * 512;

    // prologue: stage slice 0 into buf0
    gload_lds16(g1, ldsW + wave * 1024);
    if (wave < 4) gload_lds16(g2, ldsW + 8192 + wave * 1024);
    __syncthreads();

#pragma unroll 2
    for (int c = 0; c < 16; c++) {
        const int cb = (c & 1) * 6144;             // u16 offset of current buf
        const int nbB = ((c + 1) & 1) * 12288;     // byte offset of next buf
        if (c < 15) {
            gload_lds16(g1 + (c + 1) * 32, ldsW + nbB + wave * 1024);
            if (wave < 4) gload_lds16(g2 + (c + 1) * 32, ldsW + nbB + 8192 + wave * 1024);
        }
        bf16x8 af[4];
#pragma unroll
        for (int rt = 0; rt < 4; rt++)
            af[rt] = LD<F32>::v8(feat, fbase + (size_t)(wrow + rt * 16 + l15) * 512 + c * 32 + fcol);
        bf16x8 bw[6];
#pragma unroll
        for (int ct = 0; ct < 6; ct++)
            bw[ct] = *reinterpret_cast<const bf16x8*>(sW + cb + (wcol + ct * 16 + l15) * 32 + fcol);
#pragma unroll
        for (int ct = 0; ct < 6; ct++)
#pragma unroll
            for (int rt = 0; rt < 4; rt++)
                acc[rt][ct] = __builtin_amdgcn_mfma_f32_16x16x32_bf16(af[rt], bw[ct], acc[rt][ct], 0, 0, 0);
        __syncthreads();
    }

    // Epilogue: bias, scale Q, store Q/K row-major and V transposed into LDS
#pragma unroll
    for (int ct = 0; ct < 6; ct++) {
        const int lcb = wcol + ct * 16;      // 16-aligned segment within [0,192)
        const int mat = lcb >> 6;            // wave-uniform: 0=Q 1=K 2=V
        const int col = (lcb & 63) + l15;    // 0..63
        const float bias = qb[mat * 512 + h * 64 + col];
#pragma unroll
        for (int rt = 0; rt < 4; rt++) {
            const int m0 = wrow + rt * 16 + quad * 4;
            if (mat == 0) {
#pragma unroll
                for (int r = 0; r < 4; r++)
                    sQ[(m0 + r) * 72 + col] = f2bf((acc[rt][ct][r] + bias) * 0.125f);
            } else if (mat == 1) {
#pragma unroll
                for (int r = 0; r < 4; r++)
                    sK[(m0 + r) * 72 + col] = f2bf(acc[rt][ct][r] + bias);
            } else {
                u16x4 vp;
#pragma unroll
                for (int r = 0; r < 4; r++) vp[r] = f2bf(acc[rt][ct][r] + bias);
                *reinterpret_cast<u16x4*>(&sVt[col * 264 + m0]) = vp;
            }
        }
    }
    __syncthreads();

    // ---- Phase B: S = Q K^T + bias, exp, P@V, normalize ----
    bf16x8 aQ[2][2];
#pragma unroll
    for (int rt = 0; rt < 2; rt++)
#pragma unroll
        for (int s = 0; s < 2; s++)
            aQ[rt][s] = *reinterpret_cast<const bf16x8*>(
                &sQ[(wave * 32 + rt * 16 + l15) * 72 + s * 32 + quad * 8]);

    f32x4 accO[2][4];
    float rs[2][4];
#pragma unroll
    for (int rt = 0; rt < 2; rt++)
#pragma unroll
        for (int ct = 0; ct < 4; ct++) {
            f32x4 z = {0.0f, 0.0f, 0.0f, 0.0f};
            accO[rt][ct] = z;
            rs[rt][ct] = 0.0f;  // rs[rt][r]
        }

    ushort_t* sPw = sP + wave * (32 * 72);

    for (int jb = 0; jb < 4; jb++) {
        int kb = jb * 64;
        bf16x8 bK[4][2];
#pragma unroll
        for (int ctk = 0; ctk < 4; ctk++)
#pragma unroll
            for (int s = 0; s < 2; s++)
                bK[ctk][s] = *reinterpret_cast<const bf16x8*>(
                    &sK[(kb + ctk * 16 + l15) * 72 + s * 32 + quad * 8]);

#pragma unroll
        for (int ctk = 0; ctk < 4; ctk++) {
            float tcol = stb[kb + ctk * 16 + l15];
#pragma unroll
            for (int rt = 0; rt < 2; rt++) {
                f32x4 sa = {0.0f, 0.0f, 0.0f, 0.0f};
                sa = __builtin_amdgcn_mfma_f32_16x16x32_bf16(aQ[rt][0], bK[ctk][0], sa, 0, 0, 0);
                sa = __builtin_amdgcn_mfma_f32_16x16x32_bf16(aQ[rt][1], bK[ctk][1], sa, 0, 0, 0);
                int rl0 = rt * 16 + quad * 4;
#pragma unroll
                for (int r = 0; r < 4; r++) {
                    float pexp = __expf(sa[r] + tcol);  // |S|<~5, masked ~ -100, safe in f32
                    rs[rt][r] += pexp;
                    sPw[(rl0 + r) * 72 + ctk * 16 + l15] = f2bf(pexp);
                }
            }
        }

        // P @ V over this key block (wave-private P, same-wave LDS ordering, no barrier)
#pragma unroll
        for (int s = 0; s < 2; s++) {
            bf16x8 aP[2];
#pragma unroll
            for (int rt = 0; rt < 2; rt++)
                aP[rt] = *reinterpret_cast<const bf16x8*>(
                    &sPw[(rt * 16 + l15) * 72 + s * 32 + quad * 8]);
#pragma unroll
            for (int ct = 0; ct < 4; ct++) {
                bf16x8 bV = *reinterpret_cast<const bf16x8*>(
                    &sVt[(ct * 16 + l15) * 264 + kb + s * 32 + quad * 8]);
#pragma unroll
                for (int rt = 0; rt < 2; rt++)
                    accO[rt][ct] =
                        __builtin_amdgcn_mfma_f32_16x16x32_bf16(aP[rt], bV, accO[rt][ct], 0, 0, 0);
            }
        }
    }

    // Row sums: butterfly over the 16 lanes sharing a quad
    float inv_[2][4];
#pragma unroll
    for (int rt = 0; rt < 2; rt++)
#pragma unroll
        for (int r = 0; r < 4; r++) {
            float v = rs[rt][r];
            v += __shfl_xor(v, 1, 64);
            v += __shfl_xor(v, 2, 64);
            v += __shfl_xor(v, 4, 64);
            v += __shfl_xor(v, 8, 64);
            inv_[rt][r] = 1.0f / v;
        }

#pragma unroll
    for (int rt = 0; rt < 2; rt++)
#pragma unroll
        for (int ct = 0; ct < 4; ct++)
#pragma unroll
            for (int r = 0; r < 4; r++) {
                int m = wave * 32 + rt * 16 + quad * 4 + r;
                xout[((size_t)(kc * 256 + m)) * 512 + h * 64 + ct * 16 + l15] =
                    f2bf(accO[rt][ct][r] * inv_[rt][r]);
            }
}
__global__ __launch_bounds__(512, 2) void kattn_bf(const ushort_t* __restrict__ featb,
                                                   const ushort_t* __restrict__ qkv_wt,
                                                   const float* __restrict__ qb,
                                                   const void* __restrict__ pos,
                                                   const void* __restrict__ pos_w,
                                                   const int* __restrict__ mask,
                                                   const int* __restrict__ pmax,
                                                   const int* __restrict__ dtf,
                                                   ushort_t* __restrict__ xout) {
    __shared__ ushort_t sQ[256 * 72];
    __shared__ ushort_t sK[256 * 72];
    __shared__ ushort_t sVt[64 * 264];
    __shared__ ushort_t sP[8 * 32 * 72];
    __shared__ float stb[256];
    kattn_body<false>(featb, qkv_wt, qb, pos, pos_w, mask, pmax, dtf[0], xout, sQ, sK, sVt, sP, stb);
}
__global__ __launch_bounds__(512, 2) void kattn_dyn(const int* __restrict__ dtf, const void* __restrict__ feat,
                                                    const ushort_t* __restrict__ qkv_wt,
                                                    const float* __restrict__ qb,
                                                    const void* __restrict__ pos,
                                                    const void* __restrict__ pos_w,
                                                    const int* __restrict__ mask,
                                                    const int* __restrict__ pmax,
                                                    ushort_t* __restrict__ xout) {
    __shared__ ushort_t sQ[256 * 72];
    __shared__ ushort_t sK[256 * 72];
    __shared__ ushort_t sVt[64 * 264];
    __shared__ ushort_t sP[8 * 32 * 72];
    __shared__ float stb[256];
    if (dtf[0]) kattn_body<false>(feat, qkv_wt, qb, pos, pos_w, mask, pmax, 1, xout, sQ, sK, sVt, sP, stb);
    else        kattn_body<true>(feat, qkv_wt, qb, pos, pos_w, mask, pmax, 0, xout, sQ, sK, sVt, sP, stb);
}

// ---------------- K4: out = x @ proj_w + proj_b ----------------
// 512 threads (8 waves), tile 256x128, K-chunk 64: 8 iterations, each
// staging 16KB of W (dbuf 2x16KB = 32KB LDS -> 2 blocks/CU), 32 MFMA/wave
// per barrier. Task-linear staging + source chunk XOR.
template <bool F32>
static __device__ __forceinline__ void kproj_body(const ushort_t* x, const ushort_t* proj_wt,
                                                  const float* pb, void* out, ushort_t* sW) {
    const int tid = threadIdx.x;
    const int lane = tid & 63;
    const int wave = tid >> 6;   // 0..7
    const int quad = lane >> 4;
    const int l15 = lane & 15;
    const int bx = blockIdx.x;
    const int xcd = bx & 7;
    const int j = bx >> 3;                           // 0..127
    const int rowb = (xcd * 32 + (j >> 2)) * 256;    // 256-row panel
    const int colb = (j & 3) * 128;                  // 128-col block
    const int rowg = (wave >> 1) * 64;
    const int colg = (wave & 1) * 64;
    char* stg = (char*)sW;

    // staging: 1024 tasks = 128 rows x 8 chunks(16B); 2 per thread, source chunk XOR'd
    const int t0 = tid, t1 = tid + 512;
    const int r0 = t0 >> 3, r1 = t1 >> 3;
    const ushort_t* g0 = proj_wt + (size_t)(colb + r0) * 512 + (((t0 & 7) ^ (r0 & 7)) * 8);
    const ushort_t* g1 = proj_wt + (size_t)(colb + r1) * 512 + (((t1 & 7) ^ (r1 & 7)) * 8);

    f32x4 acc[4][4];
#pragma unroll
    for (int rt = 0; rt < 4; rt++)
#pragma unroll
        for (int ct = 0; ct < 4; ct++) {
            f32x4 z = {0.0f, 0.0f, 0.0f, 0.0f};
            acc[rt][ct] = z;
        }

    gload_lds16(g0, stg + t0 * 16);
    gload_lds16(g1, stg + t1 * 16);
    __syncthreads();

#pragma unroll 2
    for (int it = 0; it < 8; it++) {
        if (it < 7) {
            const int nb = ((it + 1) & 1) * 16384;
            gload_lds16(g0 + (it + 1) * 64, stg + nb + t0 * 16);
            gload_lds16(g1 + (it + 1) * 64, stg + nb + t1 * 16);
        }
        const int cbu = (it & 1) * 8192;  // u16 offset of current buf
#pragma unroll
        for (int s = 0; s < 2; s++) {
            bf16x8 af[4];
#pragma unroll
            for (int rt = 0; rt < 4; rt++) {
                int m = rowb + rowg + rt * 16 + l15;
                af[rt] = *reinterpret_cast<const bf16x8*>(
                    x + (size_t)m * 512 + it * 64 + s * 32 + quad * 8);
            }
            bf16x8 bw[4];
#pragma unroll
            for (int ct = 0; ct < 4; ct++) {
                const int rw = colg + ct * 16 + l15;
                bw[ct] = *reinterpret_cast<const bf16x8*>(
                    sW + cbu + rw * 64 + (((s * 4 + quad) ^ (rw & 7)) * 8));
            }
#pragma unroll
            for (int ct = 0; ct < 4; ct++)
#pragma unroll
                for (int rt = 0; rt < 4; rt++)
                    acc[rt][ct] = __builtin_amdgcn_mfma_f32_16x16x32_bf16(af[rt], bw[ct], acc[rt][ct], 0, 0, 0);
        }
        __syncthreads();
    }

#pragma unroll
    for (int ct = 0; ct < 4; ct++) {
        int n = colb + colg + ct * 16 + l15;
        float bias = pb[n];
#pragma unroll
        for (int rt = 0; rt < 4; rt++)
#pragma unroll
            for (int r = 0; r < 4; r++) {
                int m = rowb + rowg + rt * 16 + quad * 4 + r;
                float v = acc[rt][ct][r] + bias;
                if (F32) ((float*)out)[(size_t)m * 512 + n] = v;
                else     ((ushort_t*)out)[(size_t)m * 512 + n] = f2bf(v);
            }
    }
}
__global__ __launch_bounds__(512, 4) void kproj(const int* __restrict__ dt, const ushort_t* __restrict__ x,
                                                const ushort_t* __restrict__ proj_wt,
                                                const float* __restrict__ pb, void* __restrict__ out) {
    __shared__ ushort_t sW[16384];  // 32768 B -> 2 blocks/CU
    if (dt[0]) kproj_body<false>(x, proj_wt, pb, out, sW);
    else       kproj_body<true>(x, proj_wt, pb, out, sW);
}

extern "C" void kernel_launch(void* const* d_in, const int* in_sizes, int n_in,
                              void* d_out, int out_size, void* d_ws, size_t ws_size,
                              hipStream_t stream) {
    (void)in_sizes; (void)n_in; (void)out_size;
    const void* pos    = d_in[0];
    const void* feat   = d_in[1];
    const void* qkv_w  = d_in[2];
    const void* qkv_b  = d_in[3];
    const void* pos_w  = d_in[4];
    // d_in[5] = pos_b: softmax-invariant (constant per attention row), intentionally unused
    const void* proj_w = d_in[6];
    const void* proj_b = d_in[7];
    const int* mask    = (const int*)d_in[8];

    char* ws = (char*)d_ws;
    int* pmax         = (int*)ws;                     // ints 0,1
    int* dtf          = (int*)ws + 2;                 // int 2: dtype flag
    float* qb         = (float*)(ws + 256);           // 1536 f32
    float* pb         = (float*)(ws + 256 + 6144);    // 512 f32
    ushort_t* qkv_wt  = (ushort_t*)(ws + 16384);      // 1536x512 bf16
    ushort_t* proj_wt = qkv_wt + 786432;              // 512x512 bf16
    ushort_t* x       = proj_wt + 262144;             // 65536x512 bf16 = 64 MB
    ushort_t* featb   = x + 33554432;                 // 65536x512 bf16 = 64 MB
    const size_t NEED = 16384 + 1572864 + 524288 + 67108864 + 67108864;
    const bool big = ws_size >= NEED;

    (void)hipMemsetAsync(ws, 0, 16, stream);
    kprep<<<big ? 2561 : 513, 256, 0, stream>>>(pos, feat, qkv_w, proj_w, qkv_b, proj_b,
                                                pmax, dtf, qb, pb, featb, qkv_wt, proj_wt);
    if (big) {
        kattn_bf<<<2048, 512, 0, stream>>>(featb, qkv_wt, qb, pos, pos_w, mask, pmax, dtf, x);
    } else {
        kattn_dyn<<<2048, 512, 0, stream>>>(dtf, feat, qkv_wt, qb, pos, pos_w, mask, pmax, x);
    }
    kproj<<<1024, 512, 0, stream>>>(dtf, x, proj_wt, pb, d_out);
}